// Round 3
// baseline (517.267 us; speedup 1.0000x reference)
//
#include <hip/hip_runtime.h>
#include <hip/hip_bf16.h>

#define IN_FEAT 37
#define IN_CH 512
#define NUM_HEADS 8
#define DEPTH 64
#define BB 4
#define SS 2048
#define NROWS (BB * SS)

typedef unsigned short u16;
typedef __attribute__((ext_vector_type(8))) short bf16x8;
typedef __attribute__((ext_vector_type(4))) float f32x4;

#define MFMA16(a, b, c) __builtin_amdgcn_mfma_f32_16x16x32_bf16(a, b, c, 0, 0, 0)

__device__ __forceinline__ u16 f2bf(float f) {
    union { float f; unsigned u; } v;
    v.f = f;
    unsigned r = v.u + 0x7fffu + ((v.u >> 16) & 1u);
    return (u16)(r >> 16);
}

// ---------------------------------------------------------------------------
// Kernel 1: fused QKV projection, 32 rows/block (256 blocks = full GPU).
// q is pre-scaled by softmax_scale*log2(e) so attention works in log2 domain
// with no per-score multiply.
// ---------------------------------------------------------------------------
__global__ __launch_bounds__(256) void qkv_proj(
    const float* __restrict__ x,
    const float* __restrict__ Wq, const float* __restrict__ bq,
    const float* __restrict__ Wk, const float* __restrict__ bk,
    const float* __restrict__ Wv, const float* __restrict__ bv,
    u16* __restrict__ qo, u16* __restrict__ ko, u16* __restrict__ vo)
{
    __shared__ float xl[32][39];
    const int t = threadIdx.x;
    const int row0 = blockIdx.x * 32;
    const float QSC = 0.125f * 1.44269504f;  // 1/sqrt(64) * log2(e)

    for (int idx = t; idx < 32 * IN_FEAT; idx += 256) {
        int r = idx / IN_FEAT, i = idx - r * IN_FEAT;
        xl[r][i] = x[row0 * IN_FEAT + idx];
    }
    __syncthreads();

    // ---- Q and K ---- lane = channel-within-head, 4 row-slices
    {
        const int d = t & 63, sl = t >> 6;
        for (int h = 0; h < NUM_HEADS; ++h) {
            const int c = h * 64 + d;
            float wq[IN_FEAT], wk[IN_FEAT];
#pragma unroll
            for (int i = 0; i < IN_FEAT; ++i) {
                wq[i] = Wq[i * IN_CH + c];
                wk[i] = Wk[i * IN_CH + c];
            }
            const float bqv = bq[c], bkv = bk[c];
#pragma unroll
            for (int so = 0; so < 32; so += 4) {
                const int s = so + sl;
                float aq = bqv, ak = bkv;
#pragma unroll
                for (int i = 0; i < IN_FEAT; ++i) {
                    float xv = xl[s][i];
                    aq += xv * wq[i];
                    ak += xv * wk[i];
                }
                const int row = row0 + s;
                const int b = row >> 11, ss = row & 2047;
                const int base = ((b * NUM_HEADS + h) * SS + ss) * DEPTH + d;
                qo[base] = f2bf(aq * QSC);
                ko[base] = f2bf(ak);
            }
        }
    }
    // ---- V (transposed store) ---- lane = row, 8 d-slices
    {
        const int s = t & 31, dl = t >> 5;
        const int row = row0 + s;
        const int b = row >> 11, ss = row & 2047;
        for (int h = 0; h < NUM_HEADS; ++h) {
#pragma unroll
            for (int dof = 0; dof < 64; dof += 8) {
                const int d = dof + dl;
                const int c = h * 64 + d;
                float av = bv[c];
#pragma unroll
                for (int i = 0; i < IN_FEAT; ++i) av += xl[s][i] * Wv[i * IN_CH + c];
                vo[((b * NUM_HEADS + h) * DEPTH + d) * SS + ss] = f2bf(av);
            }
        }
    }
}

// ---------------------------------------------------------------------------
// Kernel 2: Wd fp32 [512,512] -> WdT bf16 [512,512] (transposed)
// ---------------------------------------------------------------------------
__global__ __launch_bounds__(256) void wd_trans(
    const float* __restrict__ Wd, u16* __restrict__ WdT)
{
    int idx = blockIdx.x * 256 + threadIdx.x;
    int r = idx >> 9, c = idx & 511;
    WdT[c * IN_CH + r] = f2bf(Wd[idx]);
}

// ---------------------------------------------------------------------------
// Kernel 3: flash attention, KVBLK=64, deferred max + deferred sum.
// grid (S/64, B*H) launched; block ids XCD-swizzled so each (b,h)'s 32
// q-blocks share one XCD's L2 (K/V = 2MB/XCD, L2-resident).
// Common path per 64-key step: 8 QK MFMA, 16 exp2, 16 LDS b16 writes,
// 2 b128 reads, 8 PV MFMA. NO cross-lane shuffles, NO O-rescale.
// ---------------------------------------------------------------------------
__global__ __launch_bounds__(256) void attn_kernel(
    const u16* __restrict__ qg, const u16* __restrict__ kg,
    const u16* __restrict__ vg, u16* __restrict__ og)
{
    __shared__ u16 Plds[4][16][64];  // per-wave 16x64 P tile, 16B-slab XOR swizzle
    const int tid = threadIdx.x;
    const int w = tid >> 6, lane = tid & 63;
    const int g = lane >> 4, l15 = lane & 15;
    const float THR = 8.0f;  // log2-domain defer threshold: P <= 256
    const f32x4 Z4 = {0.f, 0.f, 0.f, 0.f};

    // XCD swizzle: launched linear id -> (bx, bh) s.t. same-bh blocks share XCD
    const int lin = blockIdx.x + gridDim.x * blockIdx.y;
    const int xcd = lin & 7, t7 = lin >> 3;
    const int bx = t7 & 31, bh = xcd + 8 * (t7 >> 5);
    const int q0 = bx * 64 + w * 16;

    bf16x8 qA0 = *(const bf16x8*)&qg[(bh * SS + q0 + l15) * DEPTH + g * 8];
    bf16x8 qA1 = *(const bf16x8*)&qg[(bh * SS + q0 + l15) * DEPTH + 32 + g * 8];

    f32x4 O[4];
    float mreg[4], lreg[4];
#pragma unroll
    for (int nt = 0; nt < 4; ++nt) O[nt] = Z4;
#pragma unroll
    for (int r = 0; r < 4; ++r) { mreg[r] = -__builtin_inff(); lreg[r] = 0.f; }

    for (int kv0 = 0; kv0 < SS; kv0 += 64) {
        const u16* kb = &kg[(bh * SS + kv0) * DEPTH];
        f32x4 s[4];
#pragma unroll
        for (int kt = 0; kt < 4; ++kt) {
            bf16x8 kf0 = *(const bf16x8*)&kb[(kt * 16 + l15) * DEPTH + g * 8];
            bf16x8 kf1 = *(const bf16x8*)&kb[(kt * 16 + l15) * DEPTH + 32 + g * 8];
            f32x4 tmp = MFMA16(qA0, kf0, Z4);
            s[kt] = MFMA16(qA1, kf1, tmp);
        }
        // local (in-lane) max per row; q was pre-scaled so s is log2-domain
        float lm[4];
#pragma unroll
        for (int r = 0; r < 4; ++r)
            lm[r] = fmaxf(fmaxf(s[0][r], s[1][r]), fmaxf(s[2][r], s[3][r]));

        bool ok = (lm[0] <= mreg[0] + THR) && (lm[1] <= mreg[1] + THR) &&
                  (lm[2] <= mreg[2] + THR) && (lm[3] <= mreg[3] + THR);
        if (!__all(ok)) {  // rare: true max-reduce + rescale O and partial sums
#pragma unroll
            for (int r = 0; r < 4; ++r) {
                float mx = lm[r];
#pragma unroll
                for (int msk = 1; msk <= 8; msk <<= 1)
                    mx = fmaxf(mx, __shfl_xor(mx, msk, 64));
                float mn = fmaxf(mreg[r], mx);
                float al = exp2f(mreg[r] - mn);
                mreg[r] = mn;
                lreg[r] *= al;
#pragma unroll
                for (int nt = 0; nt < 4; ++nt) O[nt][r] *= al;
            }
        }
        // exp2 + per-lane partial sum + swizzled LDS write (C-layout -> A-layout)
#pragma unroll
        for (int kt = 0; kt < 4; ++kt) {
#pragma unroll
            for (int r = 0; r < 4; ++r) {
                float p = exp2f(s[kt][r] - mreg[r]);
                lreg[r] += p;
                const int row = g * 4 + r;
                const int f = (kt * 2 + (l15 >> 3)) ^ (row & 7);
                Plds[w][row][f * 8 + (l15 & 7)] = f2bf(p);
            }
        }
        // PV: 2 swizzled b128 reads, 8 MFMAs
#pragma unroll
        for (int hi = 0; hi < 2; ++hi) {
            const int fr = (hi * 4 + g) ^ (l15 & 7);
            bf16x8 pA = *(const bf16x8*)&Plds[w][l15][fr * 8];
            const u16* vb = &vg[bh * DEPTH * SS + kv0 + hi * 32 + g * 8];
#pragma unroll
            for (int nt = 0; nt < 4; ++nt) {
                bf16x8 bV = *(const bf16x8*)&vb[(nt * 16 + l15) * SS];
                O[nt] = MFMA16(pA, bV, O[nt]);
            }
        }
    }

    // epilogue: reduce per-lane partial sums across the 16-lane row group
#pragma unroll
    for (int r = 0; r < 4; ++r) {
#pragma unroll
        for (int msk = 1; msk <= 8; msk <<= 1)
            lreg[r] += __shfl_xor(lreg[r], msk, 64);
    }
    const int b = bh >> 3, h = bh & 7;
    float inv[4];
#pragma unroll
    for (int r = 0; r < 4; ++r) inv[r] = 1.0f / lreg[r];
#pragma unroll
    for (int nt = 0; nt < 4; ++nt)
#pragma unroll
        for (int r = 0; r < 4; ++r) {
            const int s = q0 + g * 4 + r;
            const int col = h * 64 + nt * 16 + l15;
            og[(b * SS + s) * IN_CH + col] = f2bf(O[nt][r] * inv[r]);
        }
}

// ---------------------------------------------------------------------------
// Kernel 4: output GEMM. A = attn bf16 [8192,512], BT = WdT bf16 [512,512],
// out fp32 [8192,512] = A @ Wd + bd. Block 256 = 4 waves, tile 64x64.
// ---------------------------------------------------------------------------
__global__ __launch_bounds__(256) void out_gemm(
    const u16* __restrict__ A, const u16* __restrict__ BT,
    const float* __restrict__ bd, float* __restrict__ out)
{
    const int tid = threadIdx.x;
    const int w = tid >> 6, lane = tid & 63;
    const int g = lane >> 4, l15 = lane & 15;
    const int m0 = blockIdx.x * 64 + w * 16;
    const int n0 = blockIdx.y * 64;
    const f32x4 Z4 = {0.f, 0.f, 0.f, 0.f};

    f32x4 acc[4];
#pragma unroll
    for (int nt = 0; nt < 4; ++nt) acc[nt] = Z4;

    for (int k0 = 0; k0 < IN_CH; k0 += 32) {
        bf16x8 a = *(const bf16x8*)&A[(m0 + l15) * IN_CH + k0 + g * 8];
#pragma unroll
        for (int nt = 0; nt < 4; ++nt) {
            bf16x8 b = *(const bf16x8*)&BT[(n0 + nt * 16 + l15) * IN_CH + k0 + g * 8];
            acc[nt] = MFMA16(a, b, acc[nt]);
        }
    }
#pragma unroll
    for (int nt = 0; nt < 4; ++nt)
#pragma unroll
        for (int r = 0; r < 4; ++r) {
            const int m = m0 + g * 4 + r;
            const int n = n0 + nt * 16 + l15;
            out[m * IN_CH + n] = acc[nt][r] + bd[n];
        }
}

// ---------------------------------------------------------------------------
extern "C" void kernel_launch(void* const* d_in, const int* in_sizes, int n_in,
                              void* d_out, int out_size, void* d_ws, size_t ws_size,
                              hipStream_t stream)
{
    const float* x  = (const float*)d_in[0];
    const float* Wq = (const float*)d_in[1];
    const float* bq = (const float*)d_in[2];
    const float* Wk = (const float*)d_in[3];
    const float* bk = (const float*)d_in[4];
    const float* Wv = (const float*)d_in[5];
    const float* bv = (const float*)d_in[6];
    const float* Wd = (const float*)d_in[7];
    const float* bd = (const float*)d_in[8];
    float* out = (float*)d_out;

    u16* ws  = (u16*)d_ws;
    u16* q   = ws;                       // 8192*512 bf16
    u16* k   = q + NROWS * IN_CH;        // 8192*512
    u16* vT  = k + NROWS * IN_CH;        // 8192*512 (as [B,H,D,S])
    u16* ao  = vT + NROWS * IN_CH;       // 8192*512
    u16* WdT = ao + NROWS * IN_CH;       // 512*512

    qkv_proj<<<dim3(NROWS / 32), dim3(256), 0, stream>>>(x, Wq, bq, Wk, bk, Wv, bv, q, k, vT);
    wd_trans<<<dim3(IN_CH * IN_CH / 256), dim3(256), 0, stream>>>(Wd, WdT);
    attn_kernel<<<dim3(SS / 64, BB * NUM_HEADS), dim3(256), 0, stream>>>(q, k, vT, ao);
    out_gemm<<<dim3(NROWS / 64, IN_CH / 64), dim3(256), 0, stream>>>(ao, WdT, bd, out);
}

// Round 4
// 302.254 us; speedup vs baseline: 1.7114x; 1.7114x over previous
//
#include <hip/hip_runtime.h>
#include <hip/hip_bf16.h>

#define IN_FEAT 37
#define IN_CH 512
#define NUM_HEADS 8
#define DEPTH 64
#define BB 4
#define SS 2048
#define NROWS (BB * SS)

typedef unsigned short u16;
typedef __attribute__((ext_vector_type(8))) short bf16x8;
typedef __attribute__((ext_vector_type(4))) float f32x4;

#define MFMA16(a, b, c) __builtin_amdgcn_mfma_f32_16x16x32_bf16(a, b, c, 0, 0, 0)

__device__ __forceinline__ u16 f2bf(float f) {
    union { float f; unsigned u; } v;
    v.f = f;
    unsigned r = v.u + 0x7fffu + ((v.u >> 16) & 1u);
    return (u16)(r >> 16);
}

// ---------------------------------------------------------------------------
// Kernel 0: pack everything to bf16 MFMA-ready layouts.
//  region 0: xb [8192][64]  = bf16(x), cols 37..63 zero
//  region 1: WqT/WkT/WvT [512][64] = bf16(W^T), QSC folded into WqT
//  region 2: WdT [512][512] = bf16(Wd^T)
// ---------------------------------------------------------------------------
#define XB_ELEMS (NROWS * 64)            // 524288
#define WT_ELEMS (IN_CH * 64)            // 32768
#define WD_ELEMS (IN_CH * IN_CH)         // 262144
#define PACK_TOTAL (XB_ELEMS + 3 * WT_ELEMS + WD_ELEMS)

__global__ __launch_bounds__(256) void pack_all(
    const float* __restrict__ x,
    const float* __restrict__ Wq, const float* __restrict__ Wk,
    const float* __restrict__ Wv, const float* __restrict__ Wd,
    u16* __restrict__ xb, u16* __restrict__ WqT, u16* __restrict__ WkT,
    u16* __restrict__ WvT, u16* __restrict__ WdT)
{
    const float QSC = 0.125f * 1.44269504f;  // 1/sqrt(64) * log2(e)
    int idx = blockIdx.x * 256 + threadIdx.x;
    if (idx < XB_ELEMS) {
        int row = idx >> 6, col = idx & 63;
        xb[idx] = (col < IN_FEAT) ? f2bf(x[row * IN_FEAT + col]) : (u16)0;
    } else if (idx < XB_ELEMS + 3 * WT_ELEMS) {
        int j = idx - XB_ELEMS;
        int mat = j >> 15, rem = j & (WT_ELEMS - 1);
        int c = rem >> 6, i = rem & 63;
        float v = 0.f;
        if (i < IN_FEAT) {
            if (mat == 0)      v = Wq[i * IN_CH + c] * QSC;
            else if (mat == 1) v = Wk[i * IN_CH + c];
            else               v = Wv[i * IN_CH + c];
        }
        (mat == 0 ? WqT : mat == 1 ? WkT : WvT)[rem] = f2bf(v);
    } else if (idx < PACK_TOTAL) {
        int j = idx - (XB_ELEMS + 3 * WT_ELEMS);
        int r = j >> 9, c = j & 511;
        WdT[c * IN_CH + r] = f2bf(Wd[j]);
    }
}

// ---------------------------------------------------------------------------
// Kernel 1: Q,K projection GEMM. C[s,c] = xb @ W^T, M=8192 N=512 K=64.
// Both q and k computed per block (shared A-frag). Stores into [B,H,S,D].
// ---------------------------------------------------------------------------
__global__ __launch_bounds__(256) void proj_qk(
    const u16* __restrict__ xb, const u16* __restrict__ WqT,
    const u16* __restrict__ WkT, const float* __restrict__ bqp,
    const float* __restrict__ bkp, u16* __restrict__ qo, u16* __restrict__ ko)
{
    const float QSC = 0.125f * 1.44269504f;
    const int tid = threadIdx.x;
    const int w = tid >> 6, lane = tid & 63;
    const int g = lane >> 4, l15 = lane & 15;
    const int m0 = blockIdx.x * 64 + w * 16;
    const int n0 = blockIdx.y * 64;
    const f32x4 Z4 = {0.f, 0.f, 0.f, 0.f};

    f32x4 aq[4], ak[4];
#pragma unroll
    for (int nt = 0; nt < 4; ++nt) { aq[nt] = Z4; ak[nt] = Z4; }

#pragma unroll
    for (int k0 = 0; k0 < 64; k0 += 32) {
        bf16x8 a = *(const bf16x8*)&xb[(m0 + l15) * 64 + k0 + g * 8];
#pragma unroll
        for (int nt = 0; nt < 4; ++nt) {
            bf16x8 bq8 = *(const bf16x8*)&WqT[(n0 + nt * 16 + l15) * 64 + k0 + g * 8];
            bf16x8 bk8 = *(const bf16x8*)&WkT[(n0 + nt * 16 + l15) * 64 + k0 + g * 8];
            aq[nt] = MFMA16(a, bq8, aq[nt]);
            ak[nt] = MFMA16(a, bk8, ak[nt]);
        }
    }
#pragma unroll
    for (int nt = 0; nt < 4; ++nt) {
        const int n = n0 + nt * 16 + l15;
        const float bqv = bqp[n] * QSC, bkv = bkp[n];
        const int h = n >> 6, d = n & 63;
#pragma unroll
        for (int r = 0; r < 4; ++r) {
            const int m = m0 + g * 4 + r;
            const int b = m >> 11, s = m & 2047;
            const int base = ((b * NUM_HEADS + h) * SS + s) * DEPTH + d;
            qo[base] = f2bf(aq[nt][r] + bqv);
            ko[base] = f2bf(ak[nt][r] + bkv);
        }
    }
}

// ---------------------------------------------------------------------------
// Kernel 2: V^T projection GEMM. C[c,s] = WvT @ xb^T, M=512 N=8192 K=64.
// A-frag = WvT rows, B-frag = xb rows (both contiguous). Coalesced store
// into v transposed [B,H,D,S].
// ---------------------------------------------------------------------------
__global__ __launch_bounds__(256) void proj_vT(
    const u16* __restrict__ WvT, const u16* __restrict__ xb,
    const float* __restrict__ bvp, u16* __restrict__ vo)
{
    const int tid = threadIdx.x;
    const int w = tid >> 6, lane = tid & 63;
    const int g = lane >> 4, l15 = lane & 15;
    const int m0 = blockIdx.x * 64 + w * 16;   // channel dim (512)
    const int n0 = blockIdx.y * 64;            // row dim (8192)
    const f32x4 Z4 = {0.f, 0.f, 0.f, 0.f};

    f32x4 acc[4];
#pragma unroll
    for (int nt = 0; nt < 4; ++nt) acc[nt] = Z4;

#pragma unroll
    for (int k0 = 0; k0 < 64; k0 += 32) {
        bf16x8 a = *(const bf16x8*)&WvT[(m0 + l15) * 64 + k0 + g * 8];
#pragma unroll
        for (int nt = 0; nt < 4; ++nt) {
            bf16x8 b8 = *(const bf16x8*)&xb[(n0 + nt * 16 + l15) * 64 + k0 + g * 8];
            acc[nt] = MFMA16(a, b8, acc[nt]);
        }
    }
    float bvr[4];
#pragma unroll
    for (int r = 0; r < 4; ++r) bvr[r] = bvp[m0 + g * 4 + r];
#pragma unroll
    for (int nt = 0; nt < 4; ++nt) {
#pragma unroll
        for (int r = 0; r < 4; ++r) {
            const int c = m0 + g * 4 + r;
            const int rr = n0 + nt * 16 + l15;
            const int b = rr >> 11, s = rr & 2047;
            const int h = c >> 6, d = c & 63;
            vo[((b * NUM_HEADS + h) * DEPTH + d) * SS + s] = f2bf(acc[nt][r] + bvr[r]);
        }
    }
}

// ---------------------------------------------------------------------------
// Kernel 3: flash attention, KVBLK=64, deferred max + deferred sum.
// (unchanged from round 2)
// ---------------------------------------------------------------------------
__global__ __launch_bounds__(256) void attn_kernel(
    const u16* __restrict__ qg, const u16* __restrict__ kg,
    const u16* __restrict__ vg, u16* __restrict__ og)
{
    __shared__ u16 Plds[4][16][64];
    const int tid = threadIdx.x;
    const int w = tid >> 6, lane = tid & 63;
    const int g = lane >> 4, l15 = lane & 15;
    const float THR = 8.0f;
    const f32x4 Z4 = {0.f, 0.f, 0.f, 0.f};

    const int lin = blockIdx.x + gridDim.x * blockIdx.y;
    const int xcd = lin & 7, t7 = lin >> 3;
    const int bx = t7 & 31, bh = xcd + 8 * (t7 >> 5);
    const int q0 = bx * 64 + w * 16;

    bf16x8 qA0 = *(const bf16x8*)&qg[(bh * SS + q0 + l15) * DEPTH + g * 8];
    bf16x8 qA1 = *(const bf16x8*)&qg[(bh * SS + q0 + l15) * DEPTH + 32 + g * 8];

    f32x4 O[4];
    float mreg[4], lreg[4];
#pragma unroll
    for (int nt = 0; nt < 4; ++nt) O[nt] = Z4;
#pragma unroll
    for (int r = 0; r < 4; ++r) { mreg[r] = -__builtin_inff(); lreg[r] = 0.f; }

    for (int kv0 = 0; kv0 < SS; kv0 += 64) {
        const u16* kb = &kg[(bh * SS + kv0) * DEPTH];
        f32x4 s[4];
#pragma unroll
        for (int kt = 0; kt < 4; ++kt) {
            bf16x8 kf0 = *(const bf16x8*)&kb[(kt * 16 + l15) * DEPTH + g * 8];
            bf16x8 kf1 = *(const bf16x8*)&kb[(kt * 16 + l15) * DEPTH + 32 + g * 8];
            f32x4 tmp = MFMA16(qA0, kf0, Z4);
            s[kt] = MFMA16(qA1, kf1, tmp);
        }
        float lm[4];
#pragma unroll
        for (int r = 0; r < 4; ++r)
            lm[r] = fmaxf(fmaxf(s[0][r], s[1][r]), fmaxf(s[2][r], s[3][r]));

        bool ok = (lm[0] <= mreg[0] + THR) && (lm[1] <= mreg[1] + THR) &&
                  (lm[2] <= mreg[2] + THR) && (lm[3] <= mreg[3] + THR);
        if (!__all(ok)) {
#pragma unroll
            for (int r = 0; r < 4; ++r) {
                float mx = lm[r];
#pragma unroll
                for (int msk = 1; msk <= 8; msk <<= 1)
                    mx = fmaxf(mx, __shfl_xor(mx, msk, 64));
                float mn = fmaxf(mreg[r], mx);
                float al = exp2f(mreg[r] - mn);
                mreg[r] = mn;
                lreg[r] *= al;
#pragma unroll
                for (int nt = 0; nt < 4; ++nt) O[nt][r] *= al;
            }
        }
#pragma unroll
        for (int kt = 0; kt < 4; ++kt) {
#pragma unroll
            for (int r = 0; r < 4; ++r) {
                float p = exp2f(s[kt][r] - mreg[r]);
                lreg[r] += p;
                const int row = g * 4 + r;
                const int f = (kt * 2 + (l15 >> 3)) ^ (row & 7);
                Plds[w][row][f * 8 + (l15 & 7)] = f2bf(p);
            }
        }
#pragma unroll
        for (int hi = 0; hi < 2; ++hi) {
            const int fr = (hi * 4 + g) ^ (l15 & 7);
            bf16x8 pA = *(const bf16x8*)&Plds[w][l15][fr * 8];
            const u16* vb = &vg[bh * DEPTH * SS + kv0 + hi * 32 + g * 8];
#pragma unroll
            for (int nt = 0; nt < 4; ++nt) {
                bf16x8 bV = *(const bf16x8*)&vb[(nt * 16 + l15) * SS];
                O[nt] = MFMA16(pA, bV, O[nt]);
            }
        }
    }

#pragma unroll
    for (int r = 0; r < 4; ++r) {
#pragma unroll
        for (int msk = 1; msk <= 8; msk <<= 1)
            lreg[r] += __shfl_xor(lreg[r], msk, 64);
    }
    const int b = bh >> 3, h = bh & 7;
    float inv[4];
#pragma unroll
    for (int r = 0; r < 4; ++r) inv[r] = 1.0f / lreg[r];
#pragma unroll
    for (int nt = 0; nt < 4; ++nt)
#pragma unroll
        for (int r = 0; r < 4; ++r) {
            const int s = q0 + g * 4 + r;
            const int col = h * 64 + nt * 16 + l15;
            og[(b * SS + s) * IN_CH + col] = f2bf(O[nt][r] * inv[r]);
        }
}

// ---------------------------------------------------------------------------
// Kernel 4: output GEMM (unchanged).
// ---------------------------------------------------------------------------
__global__ __launch_bounds__(256) void out_gemm(
    const u16* __restrict__ A, const u16* __restrict__ BT,
    const float* __restrict__ bd, float* __restrict__ out)
{
    const int tid = threadIdx.x;
    const int w = tid >> 6, lane = tid & 63;
    const int g = lane >> 4, l15 = lane & 15;
    const int m0 = blockIdx.x * 64 + w * 16;
    const int n0 = blockIdx.y * 64;
    const f32x4 Z4 = {0.f, 0.f, 0.f, 0.f};

    f32x4 acc[4];
#pragma unroll
    for (int nt = 0; nt < 4; ++nt) acc[nt] = Z4;

    for (int k0 = 0; k0 < IN_CH; k0 += 32) {
        bf16x8 a = *(const bf16x8*)&A[(m0 + l15) * IN_CH + k0 + g * 8];
#pragma unroll
        for (int nt = 0; nt < 4; ++nt) {
            bf16x8 b = *(const bf16x8*)&BT[(n0 + nt * 16 + l15) * IN_CH + k0 + g * 8];
            acc[nt] = MFMA16(a, b, acc[nt]);
        }
    }
#pragma unroll
    for (int nt = 0; nt < 4; ++nt)
#pragma unroll
        for (int r = 0; r < 4; ++r) {
            const int m = m0 + g * 4 + r;
            const int n = n0 + nt * 16 + l15;
            out[m * IN_CH + n] = acc[nt][r] + bd[n];
        }
}

// ---------------------------------------------------------------------------
extern "C" void kernel_launch(void* const* d_in, const int* in_sizes, int n_in,
                              void* d_out, int out_size, void* d_ws, size_t ws_size,
                              hipStream_t stream)
{
    const float* x  = (const float*)d_in[0];
    const float* Wq = (const float*)d_in[1];
    const float* bq = (const float*)d_in[2];
    const float* Wk = (const float*)d_in[3];
    const float* bk = (const float*)d_in[4];
    const float* Wv = (const float*)d_in[5];
    const float* bv = (const float*)d_in[6];
    const float* Wd = (const float*)d_in[7];
    const float* bd = (const float*)d_in[8];
    float* out = (float*)d_out;

    u16* ws  = (u16*)d_ws;
    u16* q   = ws;                        // 8192*512
    u16* k   = q + NROWS * IN_CH;         // 8192*512
    u16* vT  = k + NROWS * IN_CH;         // 8192*512 ([B,H,D,S])
    u16* ao  = vT + NROWS * IN_CH;        // 8192*512
    u16* WdT = ao + NROWS * IN_CH;        // 512*512
    u16* xb  = WdT + WD_ELEMS;            // 8192*64
    u16* WqT = xb + XB_ELEMS;             // 512*64
    u16* WkT = WqT + WT_ELEMS;            // 512*64
    u16* WvT = WkT + WT_ELEMS;            // 512*64

    pack_all<<<dim3((PACK_TOTAL + 255) / 256), dim3(256), 0, stream>>>(
        x, Wq, Wk, Wv, Wd, xb, WqT, WkT, WvT, WdT);
    proj_qk<<<dim3(NROWS / 64, IN_CH / 64), dim3(256), 0, stream>>>(
        xb, WqT, WkT, bq, bk, q, k);
    proj_vT<<<dim3(IN_CH / 64, NROWS / 64), dim3(256), 0, stream>>>(
        WvT, xb, bv, vT);
    attn_kernel<<<dim3(SS / 64, BB * NUM_HEADS), dim3(256), 0, stream>>>(q, k, vT, ao);
    out_gemm<<<dim3(NROWS / 64, IN_CH / 64), dim3(256), 0, stream>>>(ao, WdT, bd, out);
}

// Round 5
// 154.594 us; speedup vs baseline: 3.3460x; 1.9551x over previous
//
#include <hip/hip_runtime.h>
#include <hip/hip_bf16.h>
#include <stdint.h>

#define IN_FEAT 37
#define IN_CH 512
#define NUM_HEADS 8
#define DEPTH 64
#define BB 4
#define SS 2048
#define NROWS (BB * SS)

typedef unsigned short u16;
typedef __attribute__((ext_vector_type(8))) short bf16x8;
typedef __attribute__((ext_vector_type(4))) float f32x4;

#define MFMA16(a, b, c) __builtin_amdgcn_mfma_f32_16x16x32_bf16(a, b, c, 0, 0, 0)

// global_load_lds: 16B per lane, per-lane global src, wave-uniform LDS dest.
// AS casts via uintptr_t (CK idiom) so they compile under hipcc.
#define GLDS16(gsrc, ldst)                                                          \
    __builtin_amdgcn_global_load_lds(                                               \
        reinterpret_cast<const __attribute__((address_space(1))) void*>(            \
            reinterpret_cast<uintptr_t>(gsrc)),                                     \
        reinterpret_cast<__attribute__((address_space(3))) void*>(                  \
            reinterpret_cast<uintptr_t>(ldst)),                                     \
        16, 0, 0)

__device__ __forceinline__ u16 f2bf(float f) {
    union { float f; unsigned u; } v;
    v.f = f;
    unsigned r = v.u + 0x7fffu + ((v.u >> 16) & 1u);
    return (u16)(r >> 16);
}

// ---------------------------------------------------------------------------
// Kernel 0: pack to bf16 MFMA-ready layouts (unchanged).
// ---------------------------------------------------------------------------
#define XB_ELEMS (NROWS * 64)
#define WT_ELEMS (IN_CH * 64)
#define WD_ELEMS (IN_CH * IN_CH)
#define PACK_TOTAL (XB_ELEMS + 3 * WT_ELEMS + WD_ELEMS)

__global__ __launch_bounds__(256) void pack_all(
    const float* __restrict__ x,
    const float* __restrict__ Wq, const float* __restrict__ Wk,
    const float* __restrict__ Wv, const float* __restrict__ Wd,
    u16* __restrict__ xb, u16* __restrict__ WqT, u16* __restrict__ WkT,
    u16* __restrict__ WvT, u16* __restrict__ WdT)
{
    const float QSC = 0.125f * 1.44269504f;
    int idx = blockIdx.x * 256 + threadIdx.x;
    if (idx < XB_ELEMS) {
        int row = idx >> 6, col = idx & 63;
        xb[idx] = (col < IN_FEAT) ? f2bf(x[row * IN_FEAT + col]) : (u16)0;
    } else if (idx < XB_ELEMS + 3 * WT_ELEMS) {
        int j = idx - XB_ELEMS;
        int mat = j >> 15, rem = j & (WT_ELEMS - 1);
        int c = rem >> 6, i = rem & 63;
        float v = 0.f;
        if (i < IN_FEAT) {
            if (mat == 0)      v = Wq[i * IN_CH + c] * QSC;
            else if (mat == 1) v = Wk[i * IN_CH + c];
            else               v = Wv[i * IN_CH + c];
        }
        (mat == 0 ? WqT : mat == 1 ? WkT : WvT)[rem] = f2bf(v);
    } else if (idx < PACK_TOTAL) {
        int j = idx - (XB_ELEMS + 3 * WT_ELEMS);
        int r = j >> 9, c = j & 511;
        WdT[c * IN_CH + r] = f2bf(Wd[j]);
    }
}

// ---------------------------------------------------------------------------
// Kernel 1: Q,K projection GEMM. Q -> natural [B,H,S,D].
// K -> swizzled tiled layout: per (b,h), tile t = s>>6 (8KB, 64 keys x 64 d):
//   idx = bh*SS*64 + t*4096 + (s&63)*64 + (d ^ ((s&7)<<3))
// ---------------------------------------------------------------------------
__global__ __launch_bounds__(256) void proj_qk(
    const u16* __restrict__ xb, const u16* __restrict__ WqT,
    const u16* __restrict__ WkT, const float* __restrict__ bqp,
    const float* __restrict__ bkp, u16* __restrict__ qo, u16* __restrict__ ko)
{
    const float QSC = 0.125f * 1.44269504f;
    const int tid = threadIdx.x;
    const int w = tid >> 6, lane = tid & 63;
    const int g = lane >> 4, l15 = lane & 15;
    const int m0 = blockIdx.x * 64 + w * 16;
    const int n0 = blockIdx.y * 64;
    const f32x4 Z4 = {0.f, 0.f, 0.f, 0.f};

    f32x4 aq[4], ak[4];
#pragma unroll
    for (int nt = 0; nt < 4; ++nt) { aq[nt] = Z4; ak[nt] = Z4; }

#pragma unroll
    for (int k0 = 0; k0 < 64; k0 += 32) {
        bf16x8 a = *(const bf16x8*)&xb[(m0 + l15) * 64 + k0 + g * 8];
#pragma unroll
        for (int nt = 0; nt < 4; ++nt) {
            bf16x8 bq8 = *(const bf16x8*)&WqT[(n0 + nt * 16 + l15) * 64 + k0 + g * 8];
            bf16x8 bk8 = *(const bf16x8*)&WkT[(n0 + nt * 16 + l15) * 64 + k0 + g * 8];
            aq[nt] = MFMA16(a, bq8, aq[nt]);
            ak[nt] = MFMA16(a, bk8, ak[nt]);
        }
    }
#pragma unroll
    for (int nt = 0; nt < 4; ++nt) {
        const int n = n0 + nt * 16 + l15;
        const float bqv = bqp[n] * QSC, bkv = bkp[n];
        const int h = n >> 6, d = n & 63;
#pragma unroll
        for (int r = 0; r < 4; ++r) {
            const int m = m0 + g * 4 + r;
            const int b = m >> 11, s = m & 2047;
            const int bh = b * NUM_HEADS + h;
            qo[(bh * SS + s) * DEPTH + d] = f2bf(aq[nt][r] + bqv);
            ko[bh * (SS * 64) + (s >> 6) * 4096 + (s & 63) * 64 + (d ^ ((s & 7) << 3))] =
                f2bf(ak[nt][r] + bkv);
        }
    }
}

// ---------------------------------------------------------------------------
// Kernel 2: V^T projection GEMM. C[c,s] = WvT @ xb^T.
// V -> swizzled tiled layout: per (b,h), tile t = s>>6 (8KB, 64 d x 64 keys):
//   idx = bh*SS*64 + t*4096 + d*64 + ((s&63) ^ ((d&7)<<3))
// ---------------------------------------------------------------------------
__global__ __launch_bounds__(256) void proj_vT(
    const u16* __restrict__ WvT, const u16* __restrict__ xb,
    const float* __restrict__ bvp, u16* __restrict__ vo)
{
    const int tid = threadIdx.x;
    const int w = tid >> 6, lane = tid & 63;
    const int g = lane >> 4, l15 = lane & 15;
    const int m0 = blockIdx.x * 64 + w * 16;   // channel dim (512)
    const int n0 = blockIdx.y * 64;            // row dim (8192)
    const f32x4 Z4 = {0.f, 0.f, 0.f, 0.f};

    f32x4 acc[4];
#pragma unroll
    for (int nt = 0; nt < 4; ++nt) acc[nt] = Z4;

#pragma unroll
    for (int k0 = 0; k0 < 64; k0 += 32) {
        bf16x8 a = *(const bf16x8*)&WvT[(m0 + l15) * 64 + k0 + g * 8];
#pragma unroll
        for (int nt = 0; nt < 4; ++nt) {
            bf16x8 b8 = *(const bf16x8*)&xb[(n0 + nt * 16 + l15) * 64 + k0 + g * 8];
            acc[nt] = MFMA16(a, b8, acc[nt]);
        }
    }
    float bvr[4];
#pragma unroll
    for (int r = 0; r < 4; ++r) bvr[r] = bvp[m0 + g * 4 + r];
#pragma unroll
    for (int nt = 0; nt < 4; ++nt) {
#pragma unroll
        for (int r = 0; r < 4; ++r) {
            const int c = m0 + g * 4 + r;
            const int rr = n0 + nt * 16 + l15;
            const int b = rr >> 11, s = rr & 2047;
            const int h = c >> 6, d = c & 63;
            const int bh = b * NUM_HEADS + h;
            vo[bh * (SS * 64) + (s >> 6) * 4096 + d * 64 + ((s & 63) ^ ((d & 7) << 3))] =
                f2bf(acc[nt][r] + bvr[r]);
        }
    }
}

// ---------------------------------------------------------------------------
// Kernel 3: flash attention. KVBLK=64, deferred max/sum (unchanged math).
// NEW: block-cooperative double-buffered LDS staging of the pre-swizzled
// K and V tiles via global_load_lds (linear 8KB copies); all ds_reads
// 2-way-conflict-free via the baked-in XOR swizzle.
// ---------------------------------------------------------------------------
__global__ __launch_bounds__(256) void attn_kernel(
    const u16* __restrict__ qg, const u16* __restrict__ kg,
    const u16* __restrict__ vg, u16* __restrict__ og)
{
    __shared__ u16 KV[2][8192];         // [buf][ K tile 4096 | V tile 4096 ]
    __shared__ u16 Plds[4][16][64];     // per-wave P tile
    const int tid = threadIdx.x;
    const int w = tid >> 6, lane = tid & 63;
    const int g = lane >> 4, l15 = lane & 15;
    const float THR = 8.0f;
    const f32x4 Z4 = {0.f, 0.f, 0.f, 0.f};

    const int lin = blockIdx.x + gridDim.x * blockIdx.y;
    const int xcd = lin & 7, t7 = lin >> 3;
    const int bx = t7 & 31, bh = xcd + 8 * (t7 >> 5);
    const int q0 = bx * 64 + w * 16;

    const u16* ktg = kg + bh * (SS * 64);
    const u16* vtg = vg + bh * (SS * 64);
    const int soff = w * 512 + lane * 8;   // staging offset (u16), 16B/lane

    bf16x8 qA0 = *(const bf16x8*)&qg[(bh * SS + q0 + l15) * DEPTH + g * 8];
    bf16x8 qA1 = *(const bf16x8*)&qg[(bh * SS + q0 + l15) * DEPTH + 32 + g * 8];

    f32x4 O[4];
    float mreg[4], lreg[4];
#pragma unroll
    for (int nt = 0; nt < 4; ++nt) O[nt] = Z4;
#pragma unroll
    for (int r = 0; r < 4; ++r) { mreg[r] = -__builtin_inff(); lreg[r] = 0.f; }

    // stage tile t (K 8KB + V 8KB) into KV[b]; 4 glds issues per thread
    auto STAGE = [&](int b, int t) {
        const u16* ks = ktg + t * 4096 + soff;
        const u16* vs = vtg + t * 4096 + soff;
        GLDS16(ks,        &KV[b][soff - lane * 8]);
        GLDS16(ks + 2048, &KV[b][2048 + soff - lane * 8]);
        GLDS16(vs,        &KV[b][4096 + soff - lane * 8]);
        GLDS16(vs + 2048, &KV[b][6144 + soff - lane * 8]);
    };

    int cur = 0;
    STAGE(0, 0);
    __syncthreads();

    for (int t = 0; t < SS / 64; ++t) {
        if (t < SS / 64 - 1) STAGE(cur ^ 1, t + 1);

        const u16* Kb = &KV[cur][0];
        const u16* Vb = &KV[cur][4096];
        const int sw = (l15 & 7) << 3;

        f32x4 s[4];
#pragma unroll
        for (int kt = 0; kt < 4; ++kt) {
            const int rk = kt * 16 + l15;
            bf16x8 kf0 = *(const bf16x8*)&Kb[rk * 64 + ((g * 8) ^ sw)];
            bf16x8 kf1 = *(const bf16x8*)&Kb[rk * 64 + ((32 + g * 8) ^ sw)];
            f32x4 tmp = MFMA16(qA0, kf0, Z4);
            s[kt] = MFMA16(qA1, kf1, tmp);
        }

        float lm[4];
#pragma unroll
        for (int r = 0; r < 4; ++r)
            lm[r] = fmaxf(fmaxf(s[0][r], s[1][r]), fmaxf(s[2][r], s[3][r]));

        bool ok = (lm[0] <= mreg[0] + THR) && (lm[1] <= mreg[1] + THR) &&
                  (lm[2] <= mreg[2] + THR) && (lm[3] <= mreg[3] + THR);
        if (!__all(ok)) {
#pragma unroll
            for (int r = 0; r < 4; ++r) {
                float mx = lm[r];
#pragma unroll
                for (int msk = 1; msk <= 8; msk <<= 1)
                    mx = fmaxf(mx, __shfl_xor(mx, msk, 64));
                float mn = fmaxf(mreg[r], mx);
                float al = exp2f(mreg[r] - mn);
                mreg[r] = mn;
                lreg[r] *= al;
#pragma unroll
                for (int nt = 0; nt < 4; ++nt) O[nt][r] *= al;
            }
        }
#pragma unroll
        for (int kt = 0; kt < 4; ++kt) {
#pragma unroll
            for (int r = 0; r < 4; ++r) {
                float p = exp2f(s[kt][r] - mreg[r]);
                lreg[r] += p;
                const int row = g * 4 + r;
                const int f = (kt * 2 + (l15 >> 3)) ^ (row & 7);
                Plds[w][row][f * 8 + (l15 & 7)] = f2bf(p);
            }
        }
#pragma unroll
        for (int hi = 0; hi < 2; ++hi) {
            const int fr = (hi * 4 + g) ^ (l15 & 7);
            bf16x8 pA = *(const bf16x8*)&Plds[w][l15][fr * 8];
#pragma unroll
            for (int nt = 0; nt < 4; ++nt) {
                const int dr = nt * 16 + l15;
                bf16x8 bV = *(const bf16x8*)&Vb[dr * 64 + ((hi * 32 + g * 8) ^ sw)];
                O[nt] = MFMA16(pA, bV, O[nt]);
            }
        }
        __syncthreads();   // drains vmcnt (next tile staged) + all reads of cur done
        cur ^= 1;
    }

#pragma unroll
    for (int r = 0; r < 4; ++r) {
#pragma unroll
        for (int msk = 1; msk <= 8; msk <<= 1)
            lreg[r] += __shfl_xor(lreg[r], msk, 64);
    }
    const int b = bh >> 3, h = bh & 7;
    float inv[4];
#pragma unroll
    for (int r = 0; r < 4; ++r) inv[r] = 1.0f / lreg[r];
#pragma unroll
    for (int nt = 0; nt < 4; ++nt)
#pragma unroll
        for (int r = 0; r < 4; ++r) {
            const int s = q0 + g * 4 + r;
            const int col = h * 64 + nt * 16 + l15;
            og[(b * SS + s) * IN_CH + col] = f2bf(O[nt][r] * inv[r]);
        }
}

// ---------------------------------------------------------------------------
// Kernel 4: output GEMM (unchanged).
// ---------------------------------------------------------------------------
__global__ __launch_bounds__(256) void out_gemm(
    const u16* __restrict__ A, const u16* __restrict__ BT,
    const float* __restrict__ bd, float* __restrict__ out)
{
    const int tid = threadIdx.x;
    const int w = tid >> 6, lane = tid & 63;
    const int g = lane >> 4, l15 = lane & 15;
    const int m0 = blockIdx.x * 64 + w * 16;
    const int n0 = blockIdx.y * 64;
    const f32x4 Z4 = {0.f, 0.f, 0.f, 0.f};

    f32x4 acc[4];
#pragma unroll
    for (int nt = 0; nt < 4; ++nt) acc[nt] = Z4;

    for (int k0 = 0; k0 < IN_CH; k0 += 32) {
        bf16x8 a = *(const bf16x8*)&A[(m0 + l15) * IN_CH + k0 + g * 8];
#pragma unroll
        for (int nt = 0; nt < 4; ++nt) {
            bf16x8 b = *(const bf16x8*)&BT[(n0 + nt * 16 + l15) * IN_CH + k0 + g * 8];
            acc[nt] = MFMA16(a, b, acc[nt]);
        }
    }
#pragma unroll
    for (int nt = 0; nt < 4; ++nt)
#pragma unroll
        for (int r = 0; r < 4; ++r) {
            const int m = m0 + g * 4 + r;
            const int n = n0 + nt * 16 + l15;
            out[m * IN_CH + n] = acc[nt][r] + bd[n];
        }
}

// ---------------------------------------------------------------------------
extern "C" void kernel_launch(void* const* d_in, const int* in_sizes, int n_in,
                              void* d_out, int out_size, void* d_ws, size_t ws_size,
                              hipStream_t stream)
{
    const float* x  = (const float*)d_in[0];
    const float* Wq = (const float*)d_in[1];
    const float* bq = (const float*)d_in[2];
    const float* Wk = (const float*)d_in[3];
    const float* bk = (const float*)d_in[4];
    const float* Wv = (const float*)d_in[5];
    const float* bv = (const float*)d_in[6];
    const float* Wd = (const float*)d_in[7];
    const float* bd = (const float*)d_in[8];
    float* out = (float*)d_out;

    u16* ws  = (u16*)d_ws;
    u16* q   = ws;                        // 8192*512
    u16* k   = q + NROWS * IN_CH;         // 8192*512 (swizzled tiled)
    u16* vT  = k + NROWS * IN_CH;         // 8192*512 (swizzled tiled)
    u16* ao  = vT + NROWS * IN_CH;        // 8192*512
    u16* WdT = ao + NROWS * IN_CH;        // 512*512
    u16* xb  = WdT + WD_ELEMS;            // 8192*64
    u16* WqT = xb + XB_ELEMS;             // 512*64
    u16* WkT = WqT + WT_ELEMS;            // 512*64
    u16* WvT = WkT + WT_ELEMS;            // 512*64

    pack_all<<<dim3((PACK_TOTAL + 255) / 256), dim3(256), 0, stream>>>(
        x, Wq, Wk, Wv, Wd, xb, WqT, WkT, WvT, WdT);
    proj_qk<<<dim3(NROWS / 64, IN_CH / 64), dim3(256), 0, stream>>>(
        xb, WqT, WkT, bq, bk, q, k);
    proj_vT<<<dim3(IN_CH / 64, NROWS / 64), dim3(256), 0, stream>>>(
        WvT, xb, bv, vT);
    attn_kernel<<<dim3(SS / 64, BB * NUM_HEADS), dim3(256), 0, stream>>>(q, k, vT, ao);
    out_gemm<<<dim3(NROWS / 64, IN_CH / 64), dim3(256), 0, stream>>>(ao, WdT, bd, out);
}